// Round 8
// baseline (225.786 us; speedup 1.0000x reference)
//
#include <hip/hip_runtime.h>

#define HD 128

typedef __attribute__((ext_vector_type(8))) short short8;   // 8 bf16
typedef __attribute__((ext_vector_type(4))) float floatx4;  // MFMA accumulator
typedef __attribute__((ext_vector_type(2))) unsigned short ushort2v;
typedef __attribute__((ext_vector_type(4))) unsigned int uint4v;

typedef unsigned short ushort_t;
typedef unsigned int uint_t;

// ---------------------------------------------------------------- helpers ----
__device__ __forceinline__ ushort_t f2b(float f) {          // fp32 -> bf16 RNE
    union { float f; uint_t u; } v; v.f = f;
    uint_t r = v.u + 0x7fff + ((v.u >> 16) & 1);
    return (ushort_t)(r >> 16);
}
__device__ __forceinline__ short8 cvt8(const float* __restrict__ p) {
    float4 u = *(const float4*)p, v = *(const float4*)(p + 4);
    short8 r;
    r[0] = (short)f2b(u.x); r[1] = (short)f2b(u.y); r[2] = (short)f2b(u.z); r[3] = (short)f2b(u.w);
    r[4] = (short)f2b(v.x); r[5] = (short)f2b(v.y); r[6] = (short)f2b(v.z); r[7] = (short)f2b(v.w);
    return r;
}
// packed bf16 max: valid because m = relu(..) >= 0, so IEEE order == u16 order.
__device__ __forceinline__ uint_t pkmax(uint_t a, uint_t b) {
    return __builtin_bit_cast(uint_t,
        __builtin_elementwise_max(__builtin_bit_cast(ushort2v, a),
                                  __builtin_bit_cast(ushort2v, b)));
}
__device__ __forceinline__ int lbound(const int* __restrict__ dst, int E, int v) {
    int lo = 0, hi = E;
    while (lo < hi) {
        int mid = (lo + hi) >> 1;
        if (dst[mid] < v) lo = mid + 1; else hi = mid;
    }
    return lo;
}

// ------------------------------------------------------------------ prep -----
// [0,nbR): rowptr.  [nbR,nbR+nbP): W-pack.  [nbR+nbP,...): srcPad init to the
// sentinel row N (zero row), plus one block zeroes bufM's pad row.  srcPad is
// then filled by a cheap scatter inside k_gather_pool (needs rp).
__global__ __launch_bounds__(256) void k_prep(const int* __restrict__ dst, int E,
                                              int* __restrict__ rp, int N,
                                              int* __restrict__ srcPad,
                                              ushort_t* __restrict__ bufM,
                                              const float* W0, const float* W1,
                                              const float* W2, const float* W3,
                                              const float* W4, const float* W5,
                                              ushort_t* __restrict__ Wpk,
                                              int nbR, int nbP) {
    int b = blockIdx.x;
    if (b < nbR) {
        int i = b * 256 + threadIdx.x;
        if (i > N) return;
        rp[i] = lbound(dst, E, i);
    } else if (b < nbR + nbP) {
        int bb = b - nbR;
        const float* Ws[6] = {W0, W1, W2, W3, W4, W5};
        int mat = bb >> 6;
        int o = ((bb & 63) << 8) + threadIdx.x;
        int j = o & 7, l = (o >> 3) & 63, s = (o >> 9) & 3, t = o >> 11;
        int k = s * 32 + ((l >> 4) & 3) * 8 + j;
        int n = t * 16 + (l & 15);
        Wpk[(size_t)mat * 16384 + o] = f2b(Ws[mat][k * HD + n]);
    } else {
        int bb = b - nbR - nbP;
        if (bb == 0 && threadIdx.x < 64) {   // zero bufM pad row (row N, 4 groups)
            uint_t* mz = (uint_t*)bufM;
            mz[(size_t)(threadIdx.x >> 4) * ((size_t)(N + 1) * 16)
               + (size_t)N * 16 + (threadIdx.x & 15)] = 0u;
        }
        int idx = bb * 256 + threadIdx.x;
        if (idx < N * 32) srcPad[idx] = N;   // sentinel: points at zero row
    }
}

// ---------------------------------------------------------- W -> LDS stage ---
__device__ __forceinline__ void stage_w(const ushort_t* __restrict__ g,
                                        ushort_t* l, int tid) {
#pragma unroll
    for (int i = 0; i < 8; ++i) {
        int off = i * 2048 + tid * 8;
        *(short8*)&l[off] = *(const short8*)&g[off];
    }
}
__device__ __forceinline__ void stage_w_half(const ushort_t* __restrict__ g,
                                             ushort_t* l, int tid) {
#pragma unroll
    for (int i = 0; i < 4; ++i) {
        int off = i * 2048 + tid * 8;
        *(short8*)&l[off] = *(const short8*)&g[off];
    }
}

// --------------------------------------------------------------- epilogue ----
// D = mfma(Wfrag, hfrag): lane&15 = h-row, quad*4+reg = output col within tile.
__device__ __forceinline__ void store_bf16(ushort_t* __restrict__ m, int row,
                                           int colbase, const floatx4& acc,
                                           const float4& bv, bool relu, int N) {
    if (row >= N) return;
    float v0 = acc[0] + bv.x, v1 = acc[1] + bv.y, v2 = acc[2] + bv.z, v3 = acc[3] + bv.w;
    if (relu) { v0 = fmaxf(v0, 0.f); v1 = fmaxf(v1, 0.f); v2 = fmaxf(v2, 0.f); v3 = fmaxf(v3, 0.f); }
    uint2 o; o.x = (uint_t)f2b(v0) | ((uint_t)f2b(v1) << 16);
    o.y = (uint_t)f2b(v2) | ((uint_t)f2b(v3) << 16);
    *(uint2*)&m[(size_t)row * HD + colbase] = o;
}

// m is col-group-major [4 groups][N+1 rows][32 cols] bf16; row N is the zero
// pad row.  One group slice ~3.2 MB (fits a 4 MiB XCD L2); one row-slice =
// exactly one 64 B line.
__device__ __forceinline__ void store_m(ushort_t* __restrict__ m, int row,
                                        int colbase, const floatx4& acc,
                                        const float4& bv, int N) {
    if (row >= N) return;
    float v0 = fmaxf(acc[0] + bv.x, 0.f), v1 = fmaxf(acc[1] + bv.y, 0.f);
    float v2 = fmaxf(acc[2] + bv.z, 0.f), v3 = fmaxf(acc[3] + bv.w, 0.f);
    uint2 o; o.x = (uint_t)f2b(v0) | ((uint_t)f2b(v1) << 16);
    o.y = (uint_t)f2b(v2) | ((uint_t)f2b(v3) << 16);
    size_t addr = (size_t)(colbase >> 5) * ((size_t)(N + 1) * 32)
                + (size_t)row * 32 + (colbase & 31);
    *(uint2*)&m[addr] = o;
}

// ------------------------------------------------------ gather + pool GEMM ---
// Blocks [0,nb_gemm): h0 = bf16(emb[ids]); m = relu(h0 @ Wp + b).
// Blocks [nb_gemm,..): srcPad scatter — slot j = e - rp[dst[e]], j<32.
__global__ __launch_bounds__(256) void k_gather_pool(const int* __restrict__ ids,
                                                     const float* __restrict__ emb,
                                                     const ushort_t* __restrict__ Wpk,
                                                     const float* __restrict__ bias,
                                                     ushort_t* __restrict__ h0,
                                                     ushort_t* __restrict__ m, int N,
                                                     const int* __restrict__ src,
                                                     const int* __restrict__ dst,
                                                     const int* __restrict__ rp,
                                                     int* __restrict__ srcPad,
                                                     int E, int nb_gemm) {
    if ((int)blockIdx.x >= nb_gemm) {        // ---- scatter region ----
        int e = (blockIdx.x - nb_gemm) * 256 + threadIdx.x;
        if (e < E) {
            int node = dst[e];
            int j = e - rp[node];
            if (j < 32) srcPad[(size_t)node * 32 + j] = src[e];
        }
        return;
    }
    __shared__ ushort_t Wl[16384];
    int wave = blockIdx.x * 4 + (threadIdx.x >> 6);
    int row0 = wave * 32;
    int l = threadIdx.x & 63;
    int ar0 = row0 + (l & 15); if (ar0 >= N) ar0 = N - 1;
    int ar1 = ar0 + 16;        if (ar1 >= N) ar1 = N - 1;
    int ac = (l >> 4) * 8;
    int id0 = ids[ar0], id1 = ids[ar1];
    short8 a0[4], a1[4];
#pragma unroll
    for (int s = 0; s < 4; ++s) {
        a0[s] = cvt8(&emb[(size_t)id0 * HD + s * 32 + ac]);
        a1[s] = cvt8(&emb[(size_t)id1 * HD + s * 32 + ac]);
    }
    stage_w(Wpk, Wl, threadIdx.x);
    __syncthreads();
    if (row0 >= N) return;
#pragma unroll
    for (int s = 0; s < 4; ++s) {
        *(short8*)&h0[(size_t)ar0 * HD + s * 32 + ac] = a0[s];
        *(short8*)&h0[(size_t)ar1 * HD + s * 32 + ac] = a1[s];
    }
    int g0 = row0 + (l & 15), g1 = g0 + 16;
    int cb0 = ((l >> 4) & 3) * 4;
#pragma unroll
    for (int t = 0; t < 8; ++t) {
        floatx4 acc0 = {0.f, 0.f, 0.f, 0.f};
        floatx4 acc1 = {0.f, 0.f, 0.f, 0.f};
#pragma unroll
        for (int s = 0; s < 4; ++s) {
            short8 w = *(const short8*)&Wl[(t * 4 + s) * 512 + l * 8];
            acc0 = __builtin_amdgcn_mfma_f32_16x16x32_bf16(w, a0[s], acc0, 0, 0, 0);
            acc1 = __builtin_amdgcn_mfma_f32_16x16x32_bf16(w, a1[s], acc1, 0, 0, 0);
        }
        int cb = t * 16 + cb0;
        float4 bv = *(const float4*)&bias[cb];
        store_m(m, g0, cb, acc0, bv, N);
        store_m(m, g1, cb, acc1, bv, N);
    }
}

// ---------------------------------------------------------------- segmax -----
// [4][N+1][32] col-group layout.  Wave = 8 nodes, 16 slots x 4-lane quads
// (16 B/lane, one 64 B line per edge).  srcPad zero-row padding removes all
// deg predication; 16 srcPad loads then 16 independent uint4v gathers are in
// flight per wave (2x the MLP of the 4-node version — the r4/r6 data says
// this kernel is latency/concurrency-bound, not VALU- or BW-bound).  Only the
// rare deg>32 tail (Poisson-16, P~1e-4) reads rp/src.
__global__ __launch_bounds__(256) void k_segmax(const ushort_t* __restrict__ m,
                                                const int* __restrict__ srcPad,
                                                const int* __restrict__ src,
                                                const int* __restrict__ rp,
                                                ushort_t* __restrict__ agg, int N) {
    int cg = blockIdx.x & 3;
    int l = threadIdx.x & 63;
    int slot = l >> 2;                 // 0..15 edge slot
    int c = l & 3;                     // 16 B (4 u32) within the 64 B row-slice
    int node0 = ((blockIdx.x >> 2) * 4 + (threadIdx.x >> 6)) * 8;
    if (node0 >= N) return;
    const uint_t* __restrict__ mg = (const uint_t*)m + (size_t)cg * ((size_t)(N + 1) * 16);
    uint_t* __restrict__ aggw = (uint_t*)agg;

    int nd[8], s0[8], s1[8], bg[8], en[8];
#pragma unroll
    for (int nn = 0; nn < 8; ++nn) {
        int node = node0 + nn; if (node >= N) node = N - 1;
        nd[nn] = node;
    }
#pragma unroll
    for (int nn = 0; nn < 8; ++nn) {   // 16 coalesced srcPad loads in flight
        s0[nn] = srcPad[(size_t)nd[nn] * 32 + slot];
        s1[nn] = srcPad[(size_t)nd[nn] * 32 + 16 + slot];
    }
#pragma unroll
    for (int nn = 0; nn < 8; ++nn) {
        bg[nn] = rp[nd[nn]];
        en[nn] = rp[nd[nn] + 1];
    }
    uint4v p0[8], p1[8];
#pragma unroll
    for (int nn = 0; nn < 8; ++nn) {   // 16 independent gathers in flight
        p0[nn] = *(const uint4v*)&mg[(size_t)s0[nn] * 16 + c * 4];
        p1[nn] = *(const uint4v*)&mg[(size_t)s1[nn] * 16 + c * 4];
    }
    int b0 = slot & 1, b1 = (slot >> 1) & 1;
#pragma unroll
    for (int nn = 0; nn < 8; ++nn) {
        int node = node0 + nn;
        uint_t a0 = pkmax(p0[nn].x, p1[nn].x);
        uint_t a1 = pkmax(p0[nn].y, p1[nn].y);
        uint_t a2 = pkmax(p0[nn].z, p1[nn].z);
        uint_t a3 = pkmax(p0[nn].w, p1[nn].w);
        int deg = en[nn] - bg[nn];
        if (__builtin_expect(deg > 32, 0)) {   // rare tail
            int dm1 = deg - 1;
            for (int o = 32; o < deg; o += 16) {
                int i = o + slot; if (i > dm1) i = dm1;
                int s = src[bg[nn] + i];
                uint4v p = *(const uint4v*)&mg[(size_t)s * 16 + c * 4];
                a0 = pkmax(a0, p.x); a1 = pkmax(a1, p.y);
                a2 = pkmax(a2, p.z); a3 = pkmax(a3, p.w);
            }
        }
        // select-trick reduction over 16 slots (lane bits 2..5).
        uint_t q0 = b0 ? a2 : a0, q1 = b0 ? a3 : a1;
        uint_t r0 = b0 ? a0 : a2, r1 = b0 ? a1 : a3;
        q0 = pkmax(q0, (uint_t)__shfl_xor((int)r0, 4));
        q1 = pkmax(q1, (uint_t)__shfl_xor((int)r1, 4));
        uint_t s_ = b1 ? q1 : q0, t_ = b1 ? q0 : q1;
        s_ = pkmax(s_, (uint_t)__shfl_xor((int)t_, 8));
        s_ = pkmax(s_, (uint_t)__shfl_xor((int)s_, 16));
        s_ = pkmax(s_, (uint_t)__shfl_xor((int)s_, 32));
        if (slot < 4 && node < N)      // lane holds word c*4 + 2*b0 + b1
            __builtin_nontemporal_store(s_,
                &aggw[(size_t)node * 64 + cg * 16 + c * 4 + 2 * b0 + b1]);
    }
}

// ------------------------------------------- fused dual-1 + pool-2 kernel ----
// h1 = h0 @ Ws1 + agg @ Wn1 + b1  (written to global for layer-2 dual), and
// m2 = relu(h1 @ Wp2 + bp2) (written to bufM) — pool-2 is row-local, so the
// block round-trips its 128x128 h1 tile through a swizzled LDS h-tile
// (C-frag layout != A-frag layout).  W staged in temporal col-halves: LDS =
// 32 KB W + 32 KB h-tile = 64 KB (2 blocks/CU).  Same bf16 h1 values feed
// pool-2 as before (bit-identical to the separate k_pool).
// All waves execute all barriers; global stores are predicated (no early ret).
__global__ __launch_bounds__(256) void k_dual_pool(const ushort_t* __restrict__ h,
                                                   const ushort_t* __restrict__ agg,
                                                   const ushort_t* __restrict__ WsPk,
                                                   const ushort_t* __restrict__ WnPk,
                                                   const ushort_t* __restrict__ WpPk,
                                                   const float* __restrict__ bias1,
                                                   const float* __restrict__ biasP,
                                                   ushort_t* __restrict__ h1out,
                                                   ushort_t* __restrict__ m2, int N) {
    __shared__ ushort_t Wl[16384];     // 32 KB: current W col-half (Ws|Wn or Wp2)
    __shared__ ushort_t Ht[16384];     // 32 KB: 4 waves x 32 rows x 128 cols bf16
    int wave = threadIdx.x >> 6;
    int row0 = blockIdx.x * 128 + wave * 32;
    int l = threadIdx.x & 63;
    int ar0 = row0 + (l & 15); if (ar0 >= N) ar0 = N - 1;
    int ar1 = ar0 + 16;        if (ar1 >= N) ar1 = N - 1;
    int ac = (l >> 4) * 8;
    short8 ah0[4], ah1[4], ag0[4], ag1[4];
#pragma unroll
    for (int s = 0; s < 4; ++s) {
        ah0[s] = *(const short8*)&h[(size_t)ar0 * HD + s * 32 + ac];
        ah1[s] = *(const short8*)&h[(size_t)ar1 * HD + s * 32 + ac];
        ag0[s] = *(const short8*)&agg[(size_t)ar0 * HD + s * 32 + ac];
        ag1[s] = *(const short8*)&agg[(size_t)ar1 * HD + s * 32 + ac];
    }
    int g0 = row0 + (l & 15), g1 = g0 + 16;
    int cb0 = ((l >> 4) & 3) * 4;
    char* ht = (char*)(Ht + wave * 4096);          // 32 rows x 128 cols bf16
    int trow0 = l & 15, trow1 = trow0 + 16;
    int swz0 = (trow0 & 7) << 4, swz1 = swz0;      // (trow&7) identical for +16

    // ---- dual GEMM in two W col-halves ----
#pragma unroll
    for (int half = 0; half < 2; ++half) {
        if (half == 1) __syncthreads();            // done reading half 0
        stage_w_half(WsPk + half * 8192, Wl, threadIdx.x);
        stage_w_half(WnPk + half * 8192, Wl + 8192, threadIdx.x);
        __syncthreads();
#pragma unroll
        for (int t = 0; t < 4; ++t) {
            floatx4 acc0 = {0.f, 0.f, 0.f, 0.f};
            floatx4 acc1 = {0.f, 0.f, 0.f, 0.f};
#pragma unroll
            for (int s = 0; s < 4; ++s) {
                short8 ws = *(const short8*)&Wl[(t * 4 + s) * 512 + l * 8];
                acc0 = __builtin_amdgcn_mfma_f32_16x16x32_bf16(ws, ah0[s], acc0, 0, 0, 0);
                acc1 = __builtin_amdgcn_mfma_f32_16x16x32_bf16(ws, ah1[s], acc1, 0, 0, 0);
            }
#pragma unroll
            for (int s = 0; s < 4; ++s) {
                short8 wn = *(const short8*)&Wl[8192 + (t * 4 + s) * 512 + l * 8];
                acc0 = __builtin_amdgcn_mfma_f32_16x16x32_bf16(wn, ag0[s], acc0, 0, 0, 0);
                acc1 = __builtin_amdgcn_mfma_f32_16x16x32_bf16(wn, ag1[s], acc1, 0, 0, 0);
            }
            int cb = (half * 4 + t) * 16 + cb0;
            float4 bv = *(const float4*)&bias1[cb];
            uint2 o0, o1;
            o0.x = (uint_t)f2b(acc0[0] + bv.x) | ((uint_t)f2b(acc0[1] + bv.y) << 16);
            o0.y = (uint_t)f2b(acc0[2] + bv.z) | ((uint_t)f2b(acc0[3] + bv.w) << 16);
            o1.x = (uint_t)f2b(acc1[0] + bv.x) | ((uint_t)f2b(acc1[1] + bv.y) << 16);
            o1.y = (uint_t)f2b(acc1[2] + bv.z) | ((uint_t)f2b(acc1[3] + bv.w) << 16);
            if (g0 < N) *(uint2*)&h1out[(size_t)g0 * HD + cb] = o0;
            if (g1 < N) *(uint2*)&h1out[(size_t)g1 * HD + cb] = o1;
            *(uint2*)(ht + ((trow0 * 256 + cb * 2) ^ swz0)) = o0;
            *(uint2*)(ht + ((trow1 * 256 + cb * 2) ^ swz1)) = o1;
        }
    }

    // ---- pool A-fragments from own wave's h-tile (same-wave RAW; compiler
    //      inserts the lgkmcnt wait) ----
    short8 pa0[4], pa1[4];
#pragma unroll
    for (int s = 0; s < 4; ++s) {
        int colb = (s * 32 + (l >> 4) * 8) * 2;
        pa0[s] = *(const short8*)(ht + ((trow0 * 256 + colb) ^ swz0));
        pa1[s] = *(const short8*)(ht + ((trow1 * 256 + colb) ^ swz1));
    }

    // ---- pool GEMM in two W col-halves ----
#pragma unroll
    for (int half = 0; half < 2; ++half) {
        __syncthreads();                           // done reading previous Wl
        stage_w_half(WpPk + half * 8192, Wl, threadIdx.x);
        __syncthreads();
#pragma unroll
        for (int t = 0; t < 4; ++t) {
            floatx4 acc0 = {0.f, 0.f, 0.f, 0.f};
            floatx4 acc1 = {0.f, 0.f, 0.f, 0.f};
#pragma unroll
            for (int s = 0; s < 4; ++s) {
                short8 w = *(const short8*)&Wl[(t * 4 + s) * 512 + l * 8];
                acc0 = __builtin_amdgcn_mfma_f32_16x16x32_bf16(w, pa0[s], acc0, 0, 0, 0);
                acc1 = __builtin_amdgcn_mfma_f32_16x16x32_bf16(w, pa1[s], acc1, 0, 0, 0);
            }
            int cb = (half * 4 + t) * 16 + cb0;
            float4 bv = *(const float4*)&biasP[cb];
            store_m(m2, g0, cb, acc0, bv, N);
            store_m(m2, g1, cb, acc1, bv, N);
        }
    }
}

// ----------------------------------------------------------- dual GEMM -------
// out = h @ Wself + agg @ Wneigh + b; col-split (layer 2, f32 out).
template <bool F32OUT>
__global__ __launch_bounds__(256) void k_dual(const ushort_t* __restrict__ h,
                                              const ushort_t* __restrict__ agg,
                                              const ushort_t* __restrict__ WsPk,
                                              const ushort_t* __restrict__ WnPk,
                                              const float* __restrict__ bias,
                                              void* __restrict__ outp, int N) {
    __shared__ ushort_t Wl[16384];                       // Ws-half | Wn-half
    int colhalf = blockIdx.x & 1;
    int wave = (blockIdx.x >> 1) * 4 + (threadIdx.x >> 6);
    int row0 = wave * 32;
    int l = threadIdx.x & 63;
    int ar0 = row0 + (l & 15); if (ar0 >= N) ar0 = N - 1;
    int ar1 = ar0 + 16;        if (ar1 >= N) ar1 = N - 1;
    int ac = (l >> 4) * 8;
    short8 ah0[4], ah1[4], ag0[4], ag1[4];
#pragma unroll
    for (int s = 0; s < 4; ++s) {
        ah0[s] = *(const short8*)&h[(size_t)ar0 * HD + s * 32 + ac];
        ah1[s] = *(const short8*)&h[(size_t)ar1 * HD + s * 32 + ac];
        ag0[s] = *(const short8*)&agg[(size_t)ar0 * HD + s * 32 + ac];
        ag1[s] = *(const short8*)&agg[(size_t)ar1 * HD + s * 32 + ac];
    }
    stage_w_half(WsPk + colhalf * 8192, Wl, threadIdx.x);
    stage_w_half(WnPk + colhalf * 8192, Wl + 8192, threadIdx.x);
    __syncthreads();
    if (row0 >= N) return;
    int g0 = row0 + (l & 15), g1 = g0 + 16;
    int cb0 = ((l >> 4) & 3) * 4;
#pragma unroll
    for (int t = 0; t < 4; ++t) {
        floatx4 acc0 = {0.f, 0.f, 0.f, 0.f};
        floatx4 acc1 = {0.f, 0.f, 0.f, 0.f};
#pragma unroll
        for (int s = 0; s < 4; ++s) {
            short8 ws = *(const short8*)&Wl[(t * 4 + s) * 512 + l * 8];
            acc0 = __builtin_amdgcn_mfma_f32_16x16x32_bf16(ws, ah0[s], acc0, 0, 0, 0);
            acc1 = __builtin_amdgcn_mfma_f32_16x16x32_bf16(ws, ah1[s], acc1, 0, 0, 0);
        }
#pragma unroll
        for (int s = 0; s < 4; ++s) {
            short8 wn = *(const short8*)&Wl[8192 + (t * 4 + s) * 512 + l * 8];
            acc0 = __builtin_amdgcn_mfma_f32_16x16x32_bf16(wn, ag0[s], acc0, 0, 0, 0);
            acc1 = __builtin_amdgcn_mfma_f32_16x16x32_bf16(wn, ag1[s], acc1, 0, 0, 0);
        }
        int cb = (colhalf * 4 + t) * 16 + cb0;
        float4 bv = *(const float4*)&bias[cb];
        if (F32OUT) {
            float* out = (float*)outp;
            if (g0 < N) {
                float4 v = make_float4(acc0[0] + bv.x, acc0[1] + bv.y,
                                       acc0[2] + bv.z, acc0[3] + bv.w);
                *(float4*)&out[(size_t)g0 * HD + cb] = v;
            }
            if (g1 < N) {
                float4 v = make_float4(acc1[0] + bv.x, acc1[1] + bv.y,
                                       acc1[2] + bv.z, acc1[3] + bv.w);
                *(float4*)&out[(size_t)g1 * HD + cb] = v;
            }
        } else {
            ushort_t* out = (ushort_t*)outp;
            store_bf16(out, g0, cb, acc0, bv, false, N);
            store_bf16(out, g1, cb, acc1, bv, false, N);
        }
    }
}

// ---------------------------------------------------------------- launch -----
extern "C" void kernel_launch(void* const* d_in, const int* in_sizes, int n_in,
                              void* d_out, int out_size, void* d_ws, size_t ws_size,
                              hipStream_t stream) {
    const int*   node_ids = (const int*)d_in[0];
    const int*   src      = (const int*)d_in[1];
    const int*   dst      = (const int*)d_in[2];
    const float* emb      = (const float*)d_in[3];
    const float* Wp1      = (const float*)d_in[4];
    const float* bp1      = (const float*)d_in[5];
    const float* Ws1      = (const float*)d_in[6];
    const float* Wn1      = (const float*)d_in[7];
    const float* b1       = (const float*)d_in[8];
    const float* Wp2      = (const float*)d_in[9];
    const float* bp2      = (const float*)d_in[10];
    const float* Ws2      = (const float*)d_in[11];
    const float* Wn2      = (const float*)d_in[12];
    const float* b2       = (const float*)d_in[13];
    float* out = (float*)d_out;

    const int N = in_sizes[0];
    const int E = in_sizes[1];

    char* ws = (char*)d_ws;
    int* rp = (int*)ws;
    size_t off = (((size_t)(N + 1) * 4) + 255) & ~(size_t)255;
    int* srcPad = (int*)(ws + off);                      // N x 32 padded lists
    off += (((size_t)N * 32 * 4) + 255) & ~(size_t)255;
    ushort_t* Wpk  = (ushort_t*)(ws + off);              // 6 x 128x128 bf16
    ushort_t* h0   = Wpk + 6 * 16384;
    ushort_t* h1   = h0 + (size_t)N * HD;
    ushort_t* bufM = h1 + (size_t)N * HD;                // [4][N+1][32] (+pad row)
    ushort_t* bufA = bufM + (size_t)(N + 1) * HD;

    const int nbR = (N + 1 + 255) / 256;
    const int nbP = 6 * 64;
    const int nbI = ((N * 32) + 255) / 256;              // srcPad init
    const int nbE = (E + 255) / 256;                     // scatter blocks
    const int nb_gemm = (N + 127) / 128;                 // 4 waves x 32 rows
    const int nb_half = nb_gemm * 2;                     // col-split GEMMs
    const int nb_seg  = ((N + 31) / 32) * 4;             // 8 nodes/wave, 4 col-groups

    k_prep<<<nbR + nbP + nbI, 256, 0, stream>>>(dst, E, rp, N, srcPad, bufM,
                                                Wp1, Ws1, Wn1, Wp2, Ws2, Wn2,
                                                Wpk, nbR, nbP);

    const ushort_t* Wp1k = Wpk;
    const ushort_t* Ws1k = Wpk + 16384;
    const ushort_t* Wn1k = Wpk + 2 * 16384;
    const ushort_t* Wp2k = Wpk + 3 * 16384;
    const ushort_t* Ws2k = Wpk + 4 * 16384;
    const ushort_t* Wn2k = Wpk + 5 * 16384;

    // layer 1 (gather_pool also scatters srcPad in its extra blocks)
    k_gather_pool<<<nb_gemm + nbE, 256, 0, stream>>>(node_ids, emb, Wp1k, bp1,
                                                     h0, bufM, N,
                                                     src, dst, rp, srcPad, E, nb_gemm);
    k_segmax<<<nb_seg, 256, 0, stream>>>(bufM, srcPad, src, rp, bufA, N);
    // fused: dual-1 (h1) + pool-2 (bufM)
    k_dual_pool<<<nb_gemm, 256, 0, stream>>>(h0, bufA, Ws1k, Wn1k, Wp2k,
                                             b1, bp2, h1, bufM, N);
    // layer 2
    k_segmax<<<nb_seg, 256, 0, stream>>>(bufM, srcPad, src, rp, bufA, N);
    k_dual<true><<<nb_half, 256, 0, stream>>>(h1, bufA, Ws2k, Wn2k, b2, out, N);
}